// Round 8
// baseline (220.547 us; speedup 1.0000x reference)
//
#include <hip/hip_runtime.h>

// B=4096, H=200, D=32, fp32. loss = mean_over_B( sum_{H,D} (p-t)^2 * (t!=0) )
// Output: (loss, loss) -> d_out has 2 floats.
//
// n4 = 6,553,600 float4-pairs = NBLK*BLOCK*ITERS*2 exactly (2560 = 10 blocks/CU).
// R7: identical to R6 but with PLAIN cached loads (no nontemporal hint) —
// A/B test: does nt suppress Infinity-Cache hits on the restore-resident input?

#define BLOCK 256
#define NBLK  2560
#define ITERS 5
#define PFD   2

typedef float f4 __attribute__((ext_vector_type(4)));

__device__ __forceinline__ float sq_masked(f4 p, f4 t) {
    float a = 0.0f;
    float d0 = p.x - t.x, d1 = p.y - t.y, d2 = p.z - t.z, d3 = p.w - t.w;
    a += (t.x != 0.0f) ? d0 * d0 : 0.0f;
    a += (t.y != 0.0f) ? d1 * d1 : 0.0f;
    a += (t.z != 0.0f) ? d2 * d2 : 0.0f;
    a += (t.w != 0.0f) ? d3 * d3 : 0.0f;
    return a;
}

__global__ __launch_bounds__(BLOCK) void wsl_partials(const f4* __restrict__ pred,
                                                      const f4* __restrict__ targ,
                                                      float* __restrict__ partials) {
    const long T = (long)NBLK * BLOCK;                   // 655,360 threads
    const long g = (long)blockIdx.x * BLOCK + threadIdx.x;

    // Stage k covers [k*2T, (k+1)*2T); thread owns k*2T+g and k*2T+T+g.
    f4 P0[ITERS], P1[ITERS], T0[ITERS], T1[ITERS];

    #pragma unroll
    for (int k = 0; k < PFD; ++k) {
        long b = (long)k * 2 * T + g;
        P0[k] = pred[b];
        P1[k] = pred[b + T];
        T0[k] = targ[b];
        T1[k] = targ[b + T];
    }

    float acc = 0.0f;
    #pragma unroll
    for (int k = 0; k < ITERS; ++k) {
        if (k + PFD < ITERS) {                           // prefetch 2 stages ahead
            long b = (long)(k + PFD) * 2 * T + g;
            P0[k + PFD] = pred[b];
            P1[k + PFD] = pred[b + T];
            T0[k + PFD] = targ[b];
            T1[k + PFD] = targ[b + T];
        }
        acc += sq_masked(P0[k], T0[k]);
        acc += sq_masked(P1[k], T1[k]);
    }

    // wave-64 shuffle reduction
    #pragma unroll
    for (int off = 32; off > 0; off >>= 1)
        acc += __shfl_down(acc, off, 64);

    __shared__ float wsum[BLOCK / 64];
    int lane = threadIdx.x & 63;
    int wid  = threadIdx.x >> 6;
    if (lane == 0) wsum[wid] = acc;
    __syncthreads();
    if (threadIdx.x == 0) {
        float s = 0.0f;
        #pragma unroll
        for (int i = 0; i < BLOCK / 64; ++i) s += wsum[i];
        partials[blockIdx.x] = s;
    }
}

__global__ __launch_bounds__(BLOCK) void wsl_final(const float* __restrict__ partials,
                                                   int nblocks,
                                                   float* __restrict__ out,
                                                   double inv_b) {
    double acc = 0.0;
    for (int i = threadIdx.x; i < nblocks; i += BLOCK)
        acc += (double)partials[i];

    #pragma unroll
    for (int off = 32; off > 0; off >>= 1)
        acc += __shfl_down(acc, off, 64);

    __shared__ double wsum[BLOCK / 64];
    int lane = threadIdx.x & 63;
    int wid  = threadIdx.x >> 6;
    if (lane == 0) wsum[wid] = acc;
    __syncthreads();
    if (threadIdx.x == 0) {
        double s = 0.0;
        #pragma unroll
        for (int i = 0; i < BLOCK / 64; ++i) s += wsum[i];
        float v = (float)(s * inv_b);
        out[0] = v;  // loss
        out[1] = v;  // a0_loss
    }
}

extern "C" void kernel_launch(void* const* d_in, const int* in_sizes, int n_in,
                              void* d_out, int out_size, void* d_ws, size_t ws_size,
                              hipStream_t stream) {
    const f4* pred = (const f4*)d_in[0];
    const f4* targ = (const f4*)d_in[1];
    float* out = (float*)d_out;
    float* partials = (float*)d_ws;

    // n4 = 26,214,400/4 = 6,553,600 = NBLK*BLOCK*ITERS*2 exactly.
    wsl_partials<<<NBLK, BLOCK, 0, stream>>>(pred, targ, partials);
    wsl_final<<<1, BLOCK, 0, stream>>>(partials, NBLK, out, 1.0 / 4096.0);
}

// Round 9
// 200.029 us; speedup vs baseline: 1.1026x; 1.1026x over previous
//
#include <hip/hip_runtime.h>

// B=4096, H=200, D=32, fp32. loss = mean_over_B( sum_{H,D} (p-t)^2 * (t!=0) )
// Output: (loss, loss) -> d_out has 2 floats.
//
// R9: nt loads (proven 56us vs 76us cached, R6 vs R8) + single-generation
// persistent geometry: 1280 blocks = exactly 5 blocks/CU, all co-resident
// (20 waves/CU, no turnover tail). Each thread owns ITERS=20 float4-pairs,
// software-pipelined PFD=6 (~12 outstanding nt dwordx4 per lane sustained).
// n4 = 6,553,600 = NBLK*BLOCK*ITERS exactly.

#define BLOCK 256
#define NBLK  1280
#define ITERS 20
#define PFD   6

typedef float f4 __attribute__((ext_vector_type(4)));

__device__ __forceinline__ float sq_masked(f4 p, f4 t) {
    float a = 0.0f;
    float d0 = p.x - t.x, d1 = p.y - t.y, d2 = p.z - t.z, d3 = p.w - t.w;
    a += (t.x != 0.0f) ? d0 * d0 : 0.0f;
    a += (t.y != 0.0f) ? d1 * d1 : 0.0f;
    a += (t.z != 0.0f) ? d2 * d2 : 0.0f;
    a += (t.w != 0.0f) ? d3 * d3 : 0.0f;
    return a;
}

__global__ __launch_bounds__(BLOCK, 5) void wsl_partials(const f4* __restrict__ pred,
                                                         const f4* __restrict__ targ,
                                                         float* __restrict__ partials) {
    const long T = (long)NBLK * BLOCK;                   // 327,680 threads
    const long g = (long)blockIdx.x * BLOCK + threadIdx.x;

    // Stage k: thread loads pred[k*T+g], targ[k*T+g]. Static indices after
    // full unroll -> VGPR-resident; launch_bounds caps regs so the compiler
    // pipelines the 40 loads instead of hoisting them all.
    f4 P[ITERS], Tg[ITERS];

    #pragma unroll
    for (int k = 0; k < PFD; ++k) {
        long b = (long)k * T + g;
        P[k]  = __builtin_nontemporal_load(&pred[b]);
        Tg[k] = __builtin_nontemporal_load(&targ[b]);
    }

    float acc = 0.0f;
    #pragma unroll
    for (int k = 0; k < ITERS; ++k) {
        if (k + PFD < ITERS) {                           // prefetch PFD stages ahead
            long b = (long)(k + PFD) * T + g;
            P[k + PFD]  = __builtin_nontemporal_load(&pred[b]);
            Tg[k + PFD] = __builtin_nontemporal_load(&targ[b]);
        }
        acc += sq_masked(P[k], Tg[k]);
    }

    // wave-64 shuffle reduction
    #pragma unroll
    for (int off = 32; off > 0; off >>= 1)
        acc += __shfl_down(acc, off, 64);

    __shared__ float wsum[BLOCK / 64];
    int lane = threadIdx.x & 63;
    int wid  = threadIdx.x >> 6;
    if (lane == 0) wsum[wid] = acc;
    __syncthreads();
    if (threadIdx.x == 0) {
        float s = 0.0f;
        #pragma unroll
        for (int i = 0; i < BLOCK / 64; ++i) s += wsum[i];
        partials[blockIdx.x] = s;
    }
}

__global__ __launch_bounds__(BLOCK) void wsl_final(const float* __restrict__ partials,
                                                   int nblocks,
                                                   float* __restrict__ out,
                                                   double inv_b) {
    double acc = 0.0;
    for (int i = threadIdx.x; i < nblocks; i += BLOCK)
        acc += (double)partials[i];

    #pragma unroll
    for (int off = 32; off > 0; off >>= 1)
        acc += __shfl_down(acc, off, 64);

    __shared__ double wsum[BLOCK / 64];
    int lane = threadIdx.x & 63;
    int wid  = threadIdx.x >> 6;
    if (lane == 0) wsum[wid] = acc;
    __syncthreads();
    if (threadIdx.x == 0) {
        double s = 0.0;
        #pragma unroll
        for (int i = 0; i < BLOCK / 64; ++i) s += wsum[i];
        float v = (float)(s * inv_b);
        out[0] = v;  // loss
        out[1] = v;  // a0_loss
    }
}

extern "C" void kernel_launch(void* const* d_in, const int* in_sizes, int n_in,
                              void* d_out, int out_size, void* d_ws, size_t ws_size,
                              hipStream_t stream) {
    const f4* pred = (const f4*)d_in[0];
    const f4* targ = (const f4*)d_in[1];
    float* out = (float*)d_out;
    float* partials = (float*)d_ws;

    // n4 = 26,214,400/4 = 6,553,600 = NBLK*BLOCK*ITERS exactly.
    wsl_partials<<<NBLK, BLOCK, 0, stream>>>(pred, targ, partials);
    wsl_final<<<1, BLOCK, 0, stream>>>(partials, NBLK, out, 1.0 / 4096.0);
}